// Round 3
// baseline (144.387 us; speedup 1.0000x reference)
//
#include <hip/hip_runtime.h>
#include <stdint.h>

#define DIM 256
#define NQ 8
#define NLAYERS 3
#define NPAIRS 4

typedef short bf16x8 __attribute__((ext_vector_type(8)));
typedef float f32x4 __attribute__((ext_vector_type(4)));

__device__ __forceinline__ unsigned short f2bf(float f) {
  uint32_t x = __builtin_bit_cast(uint32_t, f);
  uint32_t r = (x + 0x7FFFu + ((x >> 16) & 1u)) >> 16;  // RNE
  return (unsigned short)r;
}

// ---------------------------------------------------------------------------
// Kernel 1: build U (256x256 complex fp32). One block per basis column, 256
// threads, LDS ping-pong. Wire w has bit weight 1<<(7-w). Verified round 1.
// __sincosf: angles are O(1); fast-path error ~1e-6 is negligible vs the
// 1.46e-2 output threshold.
// ---------------------------------------------------------------------------
__global__ __launch_bounds__(256) void build_U(const float* __restrict__ params,
                                               float* __restrict__ Ure,
                                               float* __restrict__ Uim) {
  __shared__ float re[2][DIM], im[2][DIM];
  const int t = threadIdx.x;
  const int col = blockIdx.x;
  int cur = 0;
  re[0][t] = (t == col) ? 1.0f : 0.0f;
  im[0][t] = 0.0f;
  __syncthreads();
  int idx = 0;
  for (int layer = 0; layer < NLAYERS; ++layer) {
    for (int p = 0; p < NPAIRS; ++p) {
      const int i = 2 * p, j = 2 * p + 1;
      const int mi = 1 << (7 - i), mj = 1 << (7 - j);
      const float p0 = params[idx + 0], p1 = params[idx + 1];
      const float p2 = params[idx + 2], p3 = params[idx + 3];
      idx += 4;
      { // RZ(p0) on wire i
        const float ang = (t & mi) ? 0.5f * p0 : -0.5f * p0;
        float sr, cr;
        __sincosf(ang, &sr, &cr);
        const float r = re[cur][t], q = im[cur][t];
        re[cur][t] = r * cr - q * sr;
        im[cur][t] = r * sr + q * cr;
      }
      __syncthreads();
      { // RX(p1) on wire j
        float s, c;
        __sincosf(0.5f * p1, &s, &c);
        const int pt = t ^ mj;
        const float rd = re[cur][t], qd = im[cur][t];
        const float rp = re[cur][pt], qp = im[cur][pt];
        re[1 - cur][t] = c * rd + s * qp;
        im[1 - cur][t] = c * qd - s * rp;
      }
      cur = 1 - cur;
      __syncthreads();
      { // CNOT(i -> j)
        const int src = (t & mi) ? (t ^ mj) : t;
        re[1 - cur][t] = re[cur][src];
        im[1 - cur][t] = im[cur][src];
      }
      cur = 1 - cur;
      __syncthreads();
      { // RZ(p2) on wire j
        const float ang = (t & mj) ? 0.5f * p2 : -0.5f * p2;
        float sr, cr;
        __sincosf(ang, &sr, &cr);
        const float r = re[cur][t], q = im[cur][t];
        re[cur][t] = r * cr - q * sr;
        im[cur][t] = r * sr + q * cr;
      }
      __syncthreads();
      { // RX(p3) on wire j
        float s, c;
        __sincosf(0.5f * p3, &s, &c);
        const int pt = t ^ mj;
        const float rd = re[cur][t], qd = im[cur][t];
        const float rp = re[cur][pt], qp = im[cur][pt];
        re[1 - cur][t] = c * rd + s * qp;
        im[1 - cur][t] = c * qd - s * rp;
      }
      cur = 1 - cur;
      __syncthreads();
    }
  }
  Ure[t * DIM + col] = re[cur][t];
  Uim[t * DIM + col] = im[cur][t];
}

// ---------------------------------------------------------------------------
// Kernel 2: A[n][k] = Re(U^H D U)[n][k], bf16, in MFMA A-operand fragment
// order (verified round 2):
//   elem(n,k) -> ((((n>>4)*8 + (k>>5))*4 + ((k>>3)&3))*16 + (n&15))*8 + (k&7)
// ---------------------------------------------------------------------------
__global__ __launch_bounds__(256) void build_A(const float* __restrict__ Ure,
                                               const float* __restrict__ Uim,
                                               short* __restrict__ Af) {
  const int n = blockIdx.x;
  const int kk = threadIdx.x;
  float acc = 0.0f;
  for (int m = 0; m < DIM; ++m) {
    const float sgn = (m < 128) ? 1.0f : -1.0f;
    const float ukr = sgn * Ure[m * DIM + n];
    const float uki = sgn * Uim[m * DIM + n];
    acc = fmaf(ukr, Ure[m * DIM + kk], acc);
    acc = fmaf(uki, Uim[m * DIM + kk], acc);
  }
  const int off =
      ((((n >> 4) * 8 + (kk >> 5)) * 4 + ((kk >> 3) & 3)) * 16 + (n & 15)) * 8 +
      (kk & 7);
  Af[off] = (short)f2bf(acc);
}

// ---------------------------------------------------------------------------
// Kernel 3 (MFMA, 2-way batch-tiled): per wave, 32 batch elements in two
// groups G=0,1: b = blockIdx*128 + w*32 + G*16 + (lane&15). Each A-fragment
// read from LDS feeds TWO mfma_f32_16x16x32_bf16 calls (one per group),
// halving LDS read traffic per output vs round 2. psi fragments built in
// registers (psi[k] = g[k>>4]*h[k&15]); in-lane epilogue dot (C col=lane&15);
// shfl_xor(16,32) reduction; sigmoid; store.
// ---------------------------------------------------------------------------
__global__ __launch_bounds__(256, 4) void qcnn_mfma(const float* __restrict__ x,
                                                    const short* __restrict__ Af,
                                                    float* __restrict__ out) {
  __shared__ short sA[16384];  // one 32 KB chunk: 64 n-rows x 256 k (bf16)
  const int tid = threadIdx.x;
  const int lane = tid & 63;
  const int w = __builtin_amdgcn_readfirstlane(tid >> 6);
  const int c = lane & 15;
  const int q = lane >> 4;
  const int lo = q & 1;
  const int hi = (q >> 1) & 1;
  const int bbase = blockIdx.x * 128 + w * 32;

  bf16x8 psi[2][8];      // B-operand fragments, per group, per 32-wide k-block
  unsigned gpk[2][8];    // g[16] packed as bf16 pairs (even low, odd high)
  float hd[2][4];        // h[q*4+r] for the epilogue dot

#pragma unroll
  for (int G = 0; G < 2; ++G) {
    const int b = bbase + G * 16 + c;
    const float4* xv = (const float4*)(x + (size_t)b * 8);
    const float4 x0 = xv[0];
    const float4 x1 = xv[1];
    const float xs[8] = {x0.x, x0.y, x0.z, x0.w, x1.x, x1.y, x1.z, x1.w};
    float cc[8], ss[8];
#pragma unroll
    for (int u = 0; u < 8; ++u) {
      cc[u] = __cosf(0.5f * xs[u]);
      ss[u] = __sinf(0.5f * xs[u]);
    }
    float g[16], h[16];
#pragma unroll
    for (int u = 0; u < 16; ++u) {
      g[u] = ((u & 8) ? ss[0] : cc[0]) * ((u & 4) ? ss[1] : cc[1]) *
             ((u & 2) ? ss[2] : cc[2]) * ((u & 1) ? ss[3] : cc[3]);
      h[u] = ((u & 8) ? ss[4] : cc[4]) * ((u & 4) ? ss[5] : cc[5]) *
             ((u & 2) ? ss[6] : cc[6]) * ((u & 1) ? ss[7] : cc[7]);
    }
    // psi frag element j of k-block t: k = 32t + 8q + j ->
    //   psi = g[2t + hi] * h[8*lo + j]
    float hs[8];
#pragma unroll
    for (int j = 0; j < 8; ++j) hs[j] = lo ? h[8 + j] : h[j];
#pragma unroll
    for (int t = 0; t < 8; ++t) {
      const float gk = hi ? g[2 * t + 1] : g[2 * t];
#pragma unroll
      for (int j = 0; j < 8; ++j) psi[G][t][j] = (short)f2bf(gk * hs[j]);
    }
#pragma unroll
    for (int r = 0; r < 4; ++r) {
      hd[G][r] = (q & 2) ? (lo ? h[12 + r] : h[8 + r])
                         : (lo ? h[4 + r] : h[r]);
    }
#pragma unroll
    for (int u = 0; u < 8; ++u) {
      gpk[G][u] = (unsigned)f2bf(g[2 * u]) |
                  ((unsigned)f2bf(g[2 * u + 1]) << 16);
    }
  }

  float z0 = 0.0f, z1 = 0.0f;
  const char* Abytes = (const char*)Af;
  char* sAbytes = (char*)sA;

#pragma unroll
  for (int nc = 0; nc < 4; ++nc) {
    if (nc) __syncthreads();  // previous chunk fully consumed
#pragma unroll
    for (int i = 0; i < 8; ++i) {
      const char* gp = Abytes + (nc * 32768 + i * 4096 + w * 1024 + lane * 16);
      char* lp = sAbytes + (i * 4096 + w * 1024);  // wave-uniform dest
      __builtin_amdgcn_global_load_lds(
          (const __attribute__((address_space(1))) uint32_t*)gp,
          (__attribute__((address_space(3))) uint32_t*)lp, 16, 0, 0);
    }
    __syncthreads();

#pragma unroll
    for (int nt = 0; nt < 4; ++nt) {
      f32x4 acc0 = {0.0f, 0.0f, 0.0f, 0.0f};
      f32x4 acc1 = {0.0f, 0.0f, 0.0f, 0.0f};
#pragma unroll
      for (int t = 0; t < 8; ++t) {
        const bf16x8 a =
            *(const bf16x8*)(sA + (nt * 4096 + t * 512 + lane * 8));
        acc0 = __builtin_amdgcn_mfma_f32_16x16x32_bf16(a, psi[0][t], acc0, 0, 0, 0);
        acc1 = __builtin_amdgcn_mfma_f32_16x16x32_bf16(a, psi[1][t], acc1, 0, 0, 0);
      }
      // rows n = (nc*4+nt)*16 + q*4 + r  ->  psi[b][n] = g[nc*4+nt] * hd[r]
      const int gi = nc * 4 + nt;
      const unsigned pe0 = gpk[0][gi >> 1], pe1 = gpk[1][gi >> 1];
      const float gv0 = __builtin_bit_cast(
          float, (gi & 1) ? (pe0 & 0xFFFF0000u) : (pe0 << 16));
      const float gv1 = __builtin_bit_cast(
          float, (gi & 1) ? (pe1 & 0xFFFF0000u) : (pe1 << 16));
      const float dot0 = hd[0][0] * acc0[0] + hd[0][1] * acc0[1] +
                         hd[0][2] * acc0[2] + hd[0][3] * acc0[3];
      const float dot1 = hd[1][0] * acc1[0] + hd[1][1] * acc1[1] +
                         hd[1][2] * acc1[2] + hd[1][3] * acc1[3];
      z0 = fmaf(gv0, dot0, z0);
      z1 = fmaf(gv1, dot1, z1);
    }
  }

  // reduce partial z across the 4 q-groups (same col lives in lanes c+16m)
  z0 += __shfl_xor(z0, 16);
  z0 += __shfl_xor(z0, 32);
  z1 += __shfl_xor(z1, 16);
  z1 += __shfl_xor(z1, 32);
  if (lane < 32) {
    const float zz = (lane < 16) ? z0 : z1;
    out[bbase + lane] = 1.0f / (1.0f + __expf(-zz));
  }
}

// ---------------------------------------------------------------------------
// ws layout: Ure[65536] f32 | Uim[65536] f32 | Af[65536] bf16  = 640 KB.
// ---------------------------------------------------------------------------
extern "C" void kernel_launch(void* const* d_in, const int* in_sizes, int n_in,
                              void* d_out, int out_size, void* d_ws, size_t ws_size,
                              hipStream_t stream) {
  const float* x = (const float*)d_in[0];
  const float* params = (const float*)d_in[1];
  float* out = (float*)d_out;
  float* Ure = (float*)d_ws;
  float* Uim = Ure + DIM * DIM;
  short* Af = (short*)(Uim + DIM * DIM);

  build_U<<<DIM, DIM, 0, stream>>>(params, Ure, Uim);
  build_A<<<DIM, DIM, 0, stream>>>(Ure, Uim, Af);

  const int B = in_sizes[0] / NQ;  // 131072
  qcnn_mfma<<<B / 128, 256, 0, stream>>>(x, Af, out);
}

// Round 4
// 138.310 us; speedup vs baseline: 1.0439x; 1.0439x over previous
//
#include <hip/hip_runtime.h>
#include <stdint.h>

#define DIM 256
#define NQ 8
#define NLAYERS 3
#define NPAIRS 4

typedef short bf16x8 __attribute__((ext_vector_type(8)));
typedef float f32x4 __attribute__((ext_vector_type(4)));

__device__ __forceinline__ unsigned short f2bf(float f) {
  uint32_t x = __builtin_bit_cast(uint32_t, f);
  uint32_t r = (x + 0x7FFFu + ((x >> 16) & 1u)) >> 16;  // RNE
  return (unsigned short)r;
}

// ---------------------------------------------------------------------------
// Kernel 1: build U (256x256 complex fp32). One block per basis column, 256
// threads, LDS ping-pong. Wire w has bit weight 1<<(7-w). Verified round 1.
// ---------------------------------------------------------------------------
__global__ __launch_bounds__(256) void build_U(const float* __restrict__ params,
                                               float* __restrict__ Ure,
                                               float* __restrict__ Uim) {
  __shared__ float re[2][DIM], im[2][DIM];
  const int t = threadIdx.x;
  const int col = blockIdx.x;
  int cur = 0;
  re[0][t] = (t == col) ? 1.0f : 0.0f;
  im[0][t] = 0.0f;
  __syncthreads();
  int idx = 0;
  for (int layer = 0; layer < NLAYERS; ++layer) {
    for (int p = 0; p < NPAIRS; ++p) {
      const int i = 2 * p, j = 2 * p + 1;
      const int mi = 1 << (7 - i), mj = 1 << (7 - j);
      const float p0 = params[idx + 0], p1 = params[idx + 1];
      const float p2 = params[idx + 2], p3 = params[idx + 3];
      idx += 4;
      { // RZ(p0) on wire i
        const float ang = (t & mi) ? 0.5f * p0 : -0.5f * p0;
        float sr, cr;
        __sincosf(ang, &sr, &cr);
        const float r = re[cur][t], q = im[cur][t];
        re[cur][t] = r * cr - q * sr;
        im[cur][t] = r * sr + q * cr;
      }
      __syncthreads();
      { // RX(p1) on wire j
        float s, c;
        __sincosf(0.5f * p1, &s, &c);
        const int pt = t ^ mj;
        const float rd = re[cur][t], qd = im[cur][t];
        const float rp = re[cur][pt], qp = im[cur][pt];
        re[1 - cur][t] = c * rd + s * qp;
        im[1 - cur][t] = c * qd - s * rp;
      }
      cur = 1 - cur;
      __syncthreads();
      { // CNOT(i -> j)
        const int src = (t & mi) ? (t ^ mj) : t;
        re[1 - cur][t] = re[cur][src];
        im[1 - cur][t] = im[cur][src];
      }
      cur = 1 - cur;
      __syncthreads();
      { // RZ(p2) on wire j
        const float ang = (t & mj) ? 0.5f * p2 : -0.5f * p2;
        float sr, cr;
        __sincosf(ang, &sr, &cr);
        const float r = re[cur][t], q = im[cur][t];
        re[cur][t] = r * cr - q * sr;
        im[cur][t] = r * sr + q * cr;
      }
      __syncthreads();
      { // RX(p3) on wire j
        float s, c;
        __sincosf(0.5f * p3, &s, &c);
        const int pt = t ^ mj;
        const float rd = re[cur][t], qd = im[cur][t];
        const float rp = re[cur][pt], qp = im[cur][pt];
        re[1 - cur][t] = c * rd + s * qp;
        im[1 - cur][t] = c * qd - s * rp;
      }
      cur = 1 - cur;
      __syncthreads();
    }
  }
  Ure[t * DIM + col] = re[cur][t];
  Uim[t * DIM + col] = im[cur][t];
}

// ---------------------------------------------------------------------------
// Kernel 2: A[n][k] = Re(U^H D U)[n][k], bf16, MFMA A-operand fragment order
// (verified rounds 2-3):
//   elem(n,k) -> ((((n>>4)*8 + (k>>5))*4 + ((k>>3)&3))*16 + (n&15))*8 + (k&7)
// v2: 1024 threads/block (4 m-chunks in parallel + LDS reduce) -> 16 waves/CU
// instead of 4, hiding the U-load latency.
// ---------------------------------------------------------------------------
__global__ __launch_bounds__(1024) void build_A(const float* __restrict__ Ure,
                                                const float* __restrict__ Uim,
                                                short* __restrict__ Af) {
  __shared__ float partial[4][DIM];
  const int n = blockIdx.x;
  const int kk = threadIdx.x & 255;
  const int mc = threadIdx.x >> 8;  // 0..3
  float acc = 0.0f;
  for (int m = mc * 64; m < mc * 64 + 64; ++m) {
    const float sgn = (m < 128) ? 1.0f : -1.0f;
    const float ukr = sgn * Ure[m * DIM + n];
    const float uki = sgn * Uim[m * DIM + n];
    acc = fmaf(ukr, Ure[m * DIM + kk], acc);
    acc = fmaf(uki, Uim[m * DIM + kk], acc);
  }
  partial[mc][kk] = acc;
  __syncthreads();
  if (mc == 0) {
    const float v = partial[0][kk] + partial[1][kk] + partial[2][kk] + partial[3][kk];
    const int off =
        ((((n >> 4) * 8 + (kk >> 5)) * 4 + ((kk >> 3) & 3)) * 16 + (n & 15)) * 8 +
        (kk & 7);
    Af[off] = (short)f2bf(v);
  }
}

// ---------------------------------------------------------------------------
// Kernel 3 (MFMA, 2-way batch-tiled): per wave, 32 batch elements in two
// groups G=0,1: b = blockIdx*128 + w*32 + G*16 + (lane&15). Each A-fragment
// LDS read feeds TWO mfma_f32_16x16x32_bf16 calls. psi built in registers
// (psi[k] = g[k>>4]*h[k&15]); in-lane epilogue dot; shfl_xor reduce; sigmoid.
//
// amdgpu_waves_per_eu(4,4): pins the occupancy target at 4 waves/EU so the
// allocator may use up to 128 VGPRs. Round 3 showed the default heuristic
// capping at 64 VGPRs and spilling ~40 regs -> 443 B/thread of scratch HBM
// traffic (116 MB writes/dispatch). Live set here is ~100 regs; 128 fits.
// ---------------------------------------------------------------------------
__global__ __launch_bounds__(256)
__attribute__((amdgpu_waves_per_eu(4, 4)))
void qcnn_mfma(const float* __restrict__ x,
               const short* __restrict__ Af,
               float* __restrict__ out) {
  __shared__ short sA[16384];  // one 32 KB chunk: 64 n-rows x 256 k (bf16)
  const int tid = threadIdx.x;
  const int lane = tid & 63;
  const int w = __builtin_amdgcn_readfirstlane(tid >> 6);
  const int c = lane & 15;
  const int q = lane >> 4;
  const int lo = q & 1;
  const int bbase = blockIdx.x * 128 + w * 32;

  bf16x8 psi[2][8];      // B-operand fragments, per group, per 32-wide k-block
  unsigned gpk[2][8];    // g[16] packed as bf16 pairs (even low, odd high)
  float hd[2][4];        // h[q*4+r] for the epilogue dot

#pragma unroll
  for (int G = 0; G < 2; ++G) {
    const int b = bbase + G * 16 + c;
    const float4* xv = (const float4*)(x + (size_t)b * 8);
    const float4 x0 = xv[0];
    const float4 x1 = xv[1];
    const float xs[8] = {x0.x, x0.y, x0.z, x0.w, x1.x, x1.y, x1.z, x1.w};
    float cc[8], ss[8];
#pragma unroll
    for (int u = 0; u < 8; ++u) {
      cc[u] = __cosf(0.5f * xs[u]);
      ss[u] = __sinf(0.5f * xs[u]);
    }
    float g[16], h[16];
#pragma unroll
    for (int u = 0; u < 16; ++u) {
      g[u] = ((u & 8) ? ss[0] : cc[0]) * ((u & 4) ? ss[1] : cc[1]) *
             ((u & 2) ? ss[2] : cc[2]) * ((u & 1) ? ss[3] : cc[3]);
      h[u] = ((u & 8) ? ss[4] : cc[4]) * ((u & 4) ? ss[5] : cc[5]) *
             ((u & 2) ? ss[6] : cc[6]) * ((u & 1) ? ss[7] : cc[7]);
    }
    // psi frag element j of k-block t: k = 32t + 8q + j ->
    //   psi = g[2t + ((q>>1)&1)] * h[8*(q&1) + j]
    float hs[8];
#pragma unroll
    for (int j = 0; j < 8; ++j) hs[j] = lo ? h[8 + j] : h[j];
#pragma unroll
    for (int t = 0; t < 8; ++t) {
      const float gk = (q >> 1) ? g[2 * t + 1] : g[2 * t];
#pragma unroll
      for (int j = 0; j < 8; ++j) psi[G][t][j] = (short)f2bf(gk * hs[j]);
    }
#pragma unroll
    for (int r = 0; r < 4; ++r) {
      hd[G][r] = (q & 2) ? (lo ? h[12 + r] : h[8 + r])
                         : (lo ? h[4 + r] : h[r]);
    }
#pragma unroll
    for (int u = 0; u < 8; ++u) {
      gpk[G][u] = (unsigned)f2bf(g[2 * u]) |
                  ((unsigned)f2bf(g[2 * u + 1]) << 16);
    }
  }

  float z0 = 0.0f, z1 = 0.0f;
  const char* Abytes = (const char*)Af;
  char* sAbytes = (char*)sA;

#pragma unroll
  for (int nc = 0; nc < 4; ++nc) {
    if (nc) __syncthreads();  // previous chunk fully consumed
#pragma unroll
    for (int i = 0; i < 8; ++i) {
      const char* gp = Abytes + (nc * 32768 + i * 4096 + w * 1024 + lane * 16);
      char* lp = sAbytes + (i * 4096 + w * 1024);  // wave-uniform dest
      __builtin_amdgcn_global_load_lds(
          (const __attribute__((address_space(1))) uint32_t*)gp,
          (__attribute__((address_space(3))) uint32_t*)lp, 16, 0, 0);
    }
    __syncthreads();

#pragma unroll
    for (int nt = 0; nt < 4; ++nt) {
      f32x4 acc0 = {0.0f, 0.0f, 0.0f, 0.0f};
      f32x4 acc1 = {0.0f, 0.0f, 0.0f, 0.0f};
#pragma unroll
      for (int t = 0; t < 8; ++t) {
        const bf16x8 a =
            *(const bf16x8*)(sA + (nt * 4096 + t * 512 + lane * 8));
        acc0 = __builtin_amdgcn_mfma_f32_16x16x32_bf16(a, psi[0][t], acc0, 0, 0, 0);
        acc1 = __builtin_amdgcn_mfma_f32_16x16x32_bf16(a, psi[1][t], acc1, 0, 0, 0);
      }
      // rows n = (nc*4+nt)*16 + q*4 + r  ->  psi[b][n] = g[nc*4+nt] * hd[r]
      const int gi = nc * 4 + nt;
      const unsigned pe0 = gpk[0][gi >> 1], pe1 = gpk[1][gi >> 1];
      const float gv0 = __builtin_bit_cast(
          float, (gi & 1) ? (pe0 & 0xFFFF0000u) : (pe0 << 16));
      const float gv1 = __builtin_bit_cast(
          float, (gi & 1) ? (pe1 & 0xFFFF0000u) : (pe1 << 16));
      const float dot0 = hd[0][0] * acc0[0] + hd[0][1] * acc0[1] +
                         hd[0][2] * acc0[2] + hd[0][3] * acc0[3];
      const float dot1 = hd[1][0] * acc1[0] + hd[1][1] * acc1[1] +
                         hd[1][2] * acc1[2] + hd[1][3] * acc1[3];
      z0 = fmaf(gv0, dot0, z0);
      z1 = fmaf(gv1, dot1, z1);
    }
  }

  // reduce partial z across the 4 q-groups (same col lives in lanes c+16m)
  z0 += __shfl_xor(z0, 16);
  z0 += __shfl_xor(z0, 32);
  z1 += __shfl_xor(z1, 16);
  z1 += __shfl_xor(z1, 32);
  if (lane < 32) {
    const float zz = (lane < 16) ? z0 : z1;
    out[bbase + lane] = 1.0f / (1.0f + __expf(-zz));
  }
}

// ---------------------------------------------------------------------------
// ws layout: Ure[65536] f32 | Uim[65536] f32 | Af[65536] bf16  = 640 KB.
// ---------------------------------------------------------------------------
extern "C" void kernel_launch(void* const* d_in, const int* in_sizes, int n_in,
                              void* d_out, int out_size, void* d_ws, size_t ws_size,
                              hipStream_t stream) {
  const float* x = (const float*)d_in[0];
  const float* params = (const float*)d_in[1];
  float* out = (float*)d_out;
  float* Ure = (float*)d_ws;
  float* Uim = Ure + DIM * DIM;
  short* Af = (short*)(Uim + DIM * DIM);

  build_U<<<DIM, DIM, 0, stream>>>(params, Ure, Uim);
  build_A<<<DIM, 1024, 0, stream>>>(Ure, Uim, Af);

  const int B = in_sizes[0] / NQ;  // 131072
  qcnn_mfma<<<B / 128, 256, 0, stream>>>(x, Af, out);
}

// Round 5
// 89.691 us; speedup vs baseline: 1.6098x; 1.5421x over previous
//
#include <hip/hip_runtime.h>
#include <stdint.h>

#define DIM 256
#define NQ 8
#define NLAYERS 3
#define NPAIRS 4

typedef short bf16x8 __attribute__((ext_vector_type(8)));
typedef float f32x4 __attribute__((ext_vector_type(4)));

__device__ __forceinline__ unsigned short f2bf(float f) {
  uint32_t x = __builtin_bit_cast(uint32_t, f);
  uint32_t r = (x + 0x7FFFu + ((x >> 16) & 1u)) >> 16;  // RNE
  return (unsigned short)r;
}

// ---------------------------------------------------------------------------
// Kernel 1: build U (256x256 complex fp32). One block per basis column, 256
// threads, LDS ping-pong. Wire w has bit weight 1<<(7-w). Verified round 1.
// ---------------------------------------------------------------------------
__global__ __launch_bounds__(256) void build_U(const float* __restrict__ params,
                                               float* __restrict__ Ure,
                                               float* __restrict__ Uim) {
  __shared__ float re[2][DIM], im[2][DIM];
  const int t = threadIdx.x;
  const int col = blockIdx.x;
  int cur = 0;
  re[0][t] = (t == col) ? 1.0f : 0.0f;
  im[0][t] = 0.0f;
  __syncthreads();
  int idx = 0;
  for (int layer = 0; layer < NLAYERS; ++layer) {
    for (int p = 0; p < NPAIRS; ++p) {
      const int i = 2 * p, j = 2 * p + 1;
      const int mi = 1 << (7 - i), mj = 1 << (7 - j);
      const float p0 = params[idx + 0], p1 = params[idx + 1];
      const float p2 = params[idx + 2], p3 = params[idx + 3];
      idx += 4;
      { // RZ(p0) on wire i
        const float ang = (t & mi) ? 0.5f * p0 : -0.5f * p0;
        float sr, cr;
        __sincosf(ang, &sr, &cr);
        const float r = re[cur][t], q = im[cur][t];
        re[cur][t] = r * cr - q * sr;
        im[cur][t] = r * sr + q * cr;
      }
      __syncthreads();
      { // RX(p1) on wire j
        float s, c;
        __sincosf(0.5f * p1, &s, &c);
        const int pt = t ^ mj;
        const float rd = re[cur][t], qd = im[cur][t];
        const float rp = re[cur][pt], qp = im[cur][pt];
        re[1 - cur][t] = c * rd + s * qp;
        im[1 - cur][t] = c * qd - s * rp;
      }
      cur = 1 - cur;
      __syncthreads();
      { // CNOT(i -> j)
        const int src = (t & mi) ? (t ^ mj) : t;
        re[1 - cur][t] = re[cur][src];
        im[1 - cur][t] = im[cur][src];
      }
      cur = 1 - cur;
      __syncthreads();
      { // RZ(p2) on wire j
        const float ang = (t & mj) ? 0.5f * p2 : -0.5f * p2;
        float sr, cr;
        __sincosf(ang, &sr, &cr);
        const float r = re[cur][t], q = im[cur][t];
        re[cur][t] = r * cr - q * sr;
        im[cur][t] = r * sr + q * cr;
      }
      __syncthreads();
      { // RX(p3) on wire j
        float s, c;
        __sincosf(0.5f * p3, &s, &c);
        const int pt = t ^ mj;
        const float rd = re[cur][t], qd = im[cur][t];
        const float rp = re[cur][pt], qp = im[cur][pt];
        re[1 - cur][t] = c * rd + s * qp;
        im[1 - cur][t] = c * qd - s * rp;
      }
      cur = 1 - cur;
      __syncthreads();
    }
  }
  Ure[t * DIM + col] = re[cur][t];
  Uim[t * DIM + col] = im[cur][t];
}

// ---------------------------------------------------------------------------
// Kernel 2: A[n][k] = Re(U^H D U)[n][k], bf16, MFMA A-operand fragment order
// (verified rounds 2-4):
//   elem(n,k) -> ((((n>>4)*8 + (k>>5))*4 + ((k>>3)&3))*16 + (n&15))*8 + (k&7)
// 1024 threads/block: 4 m-chunks in parallel + LDS reduce.
// ---------------------------------------------------------------------------
__global__ __launch_bounds__(1024) void build_A(const float* __restrict__ Ure,
                                                const float* __restrict__ Uim,
                                                short* __restrict__ Af) {
  __shared__ float partial[4][DIM];
  const int n = blockIdx.x;
  const int kk = threadIdx.x & 255;
  const int mc = threadIdx.x >> 8;  // 0..3
  float acc = 0.0f;
  for (int m = mc * 64; m < mc * 64 + 64; ++m) {
    const float sgn = (m < 128) ? 1.0f : -1.0f;
    const float ukr = sgn * Ure[m * DIM + n];
    const float uki = sgn * Uim[m * DIM + n];
    acc = fmaf(ukr, Ure[m * DIM + kk], acc);
    acc = fmaf(uki, Uim[m * DIM + kk], acc);
  }
  partial[mc][kk] = acc;
  __syncthreads();
  if (mc == 0) {
    const float v = partial[0][kk] + partial[1][kk] + partial[2][kk] + partial[3][kk];
    const int off =
        ((((n >> 4) * 8 + (kk >> 5)) * 4 + ((kk >> 3) & 3)) * 16 + (n & 15)) * 8 +
        (kk & 7);
    Af[off] = (short)f2bf(v);
  }
}

// ---------------------------------------------------------------------------
// Kernel 3 (MFMA, single-group, spill-free by construction): per wave, 16
// batch elements b = blockIdx*64 + w*16 + (lane&15).
// Register budget is the design constraint (allocator pins 256-thread kernels
// at 64 arch VGPRs; rounds 3/4 proved hints don't move it):
//   psi[8] B-frags       32 VGPR   (irreducible: 16 b x 256 k)
//   cc/ss wires 0-3       8 VGPR   (epilogue g recomputed per tile: 3 v_mul,
//                                   compile-time selects - replaces gpk[])
//   hd[4]                 4 VGPR
//   addresses/z/misc    ~10 VGPR
//   acc                   4 AGPR
// g[16]/h[16] are never materialized; hs/gk are built by select-trees and die
// after psi construction. Steady live set ~54 < 64 -> zero scratch.
// ---------------------------------------------------------------------------
__global__ __launch_bounds__(256, 8) void qcnn_mfma(const float* __restrict__ x,
                                                    const short* __restrict__ Af,
                                                    float* __restrict__ out) {
  __shared__ short sA[16384];  // one 32 KB chunk: 64 n-rows x 256 k (bf16)
  const int tid = threadIdx.x;
  const int lane = tid & 63;
  const int w = __builtin_amdgcn_readfirstlane(tid >> 6);
  const int c = lane & 15;
  const int q = lane >> 4;
  const int lo = q & 1;
  const int hi = (q >> 1) & 1;
  const int b = blockIdx.x * 64 + w * 16 + c;

  const float4* xv = (const float4*)(x + (size_t)b * 8);
  const float4 x0 = xv[0];
  const float4 x1 = xv[1];
  const float xs[8] = {x0.x, x0.y, x0.z, x0.w, x1.x, x1.y, x1.z, x1.w};
  float cc[8], ss[8];
#pragma unroll
  for (int u = 0; u < 8; ++u) {
    cc[u] = __cosf(0.5f * xs[u]);
    ss[u] = __sinf(0.5f * xs[u]);
  }

  // hs[j] = h[8*lo + j] = (lo?ss4:cc4)*(j&4?ss5:cc5)*(j&2?ss6:cc6)*(j&1?ss7:cc7)
  float hs[8];
  {
    const float a = lo ? ss[4] : cc[4];
    const float b0 = a * cc[5], b1 = a * ss[5];
    const float c0 = b0 * cc[6], c1 = b0 * ss[6];
    const float c2 = b1 * cc[6], c3 = b1 * ss[6];
    hs[0] = c0 * cc[7]; hs[1] = c0 * ss[7];
    hs[2] = c1 * cc[7]; hs[3] = c1 * ss[7];
    hs[4] = c2 * cc[7]; hs[5] = c2 * ss[7];
    hs[6] = c3 * cc[7]; hs[7] = c3 * ss[7];
  }
  // gk[t] = g[2t + hi] = (t&4?ss0:cc0)*(t&2?ss1:cc1)*(t&1?ss2:cc2)*(hi?ss3:cc3)
  float gk[8];
  {
    const float g3 = hi ? ss[3] : cc[3];
    const float d0 = cc[2] * g3, d1 = ss[2] * g3;
    const float e0 = cc[1] * d0, e1 = cc[1] * d1;
    const float e2 = ss[1] * d0, e3 = ss[1] * d1;
    gk[0] = cc[0] * e0; gk[1] = cc[0] * e1;
    gk[2] = cc[0] * e2; gk[3] = cc[0] * e3;
    gk[4] = ss[0] * e0; gk[5] = ss[0] * e1;
    gk[6] = ss[0] * e2; gk[7] = ss[0] * e3;
  }
  // hd[r] = h[8*hi + 4*lo + r] (epilogue dot weights)
  float hd[4];
  {
    const float head = (hi ? ss[4] : cc[4]) * (lo ? ss[5] : cc[5]);
    const float h0 = head * cc[6], h1 = head * ss[6];
    hd[0] = h0 * cc[7]; hd[1] = h0 * ss[7];
    hd[2] = h1 * cc[7]; hd[3] = h1 * ss[7];
  }
  // psi frag for k-block t: element j is psi_b[32t + 8q + j] = gk[t]*hs[j]
  bf16x8 psi[8];
#pragma unroll
  for (int t = 0; t < 8; ++t) {
#pragma unroll
    for (int j = 0; j < 8; ++j) psi[t][j] = (short)f2bf(gk[t] * hs[j]);
  }

  float z = 0.0f;
  const char* Abytes = (const char*)Af;
  char* sAbytes = (char*)sA;

#pragma unroll
  for (int nc = 0; nc < 4; ++nc) {
    if (nc) __syncthreads();  // previous chunk fully consumed
#pragma unroll
    for (int i = 0; i < 8; ++i) {
      const char* gp = Abytes + (nc * 32768 + i * 4096 + w * 1024 + lane * 16);
      char* lp = sAbytes + (i * 4096 + w * 1024);  // wave-uniform dest
      __builtin_amdgcn_global_load_lds(
          (const __attribute__((address_space(1))) uint32_t*)gp,
          (__attribute__((address_space(3))) uint32_t*)lp, 16, 0, 0);
    }
    __syncthreads();

#pragma unroll
    for (int nt = 0; nt < 4; ++nt) {
      f32x4 acc = {0.0f, 0.0f, 0.0f, 0.0f};
#pragma unroll
      for (int t = 0; t < 8; ++t) {
        const bf16x8 a =
            *(const bf16x8*)(sA + (nt * 4096 + t * 512 + lane * 8));
        acc = __builtin_amdgcn_mfma_f32_16x16x32_bf16(a, psi[t], acc, 0, 0, 0);
      }
      // rows n = (nc*4+nt)*16 + q*4 + r -> psi[b][n] = g[nc*4+nt] * hd[r]
      const int gi = nc * 4 + nt;  // compile-time constant per iteration
      const float gv = ((gi & 8) ? ss[0] : cc[0]) * ((gi & 4) ? ss[1] : cc[1]) *
                       ((gi & 2) ? ss[2] : cc[2]) * ((gi & 1) ? ss[3] : cc[3]);
      const float dot =
          hd[0] * acc[0] + hd[1] * acc[1] + hd[2] * acc[2] + hd[3] * acc[3];
      z = fmaf(gv, dot, z);
    }
  }

  // reduce partial z across the 4 q-groups (same col lives in lanes c+16m)
  z += __shfl_xor(z, 16);
  z += __shfl_xor(z, 32);
  if (lane < 16) {
    out[blockIdx.x * 64 + w * 16 + lane] = 1.0f / (1.0f + __expf(-z));
  }
}

// ---------------------------------------------------------------------------
// ws layout: Ure[65536] f32 | Uim[65536] f32 | Af[65536] bf16  = 640 KB.
// ---------------------------------------------------------------------------
extern "C" void kernel_launch(void* const* d_in, const int* in_sizes, int n_in,
                              void* d_out, int out_size, void* d_ws, size_t ws_size,
                              hipStream_t stream) {
  const float* x = (const float*)d_in[0];
  const float* params = (const float*)d_in[1];
  float* out = (float*)d_out;
  float* Ure = (float*)d_ws;
  float* Uim = Ure + DIM * DIM;
  short* Af = (short*)(Uim + DIM * DIM);

  build_U<<<DIM, DIM, 0, stream>>>(params, Ure, Uim);
  build_A<<<DIM, 1024, 0, stream>>>(Ure, Uim, Af);

  const int B = in_sizes[0] / NQ;  // 131072
  qcnn_mfma<<<B / 64, 256, 0, stream>>>(x, Af, out);
}